// Round 1
// 503.561 us; speedup vs baseline: 1.0114x; 1.0114x over previous
//
#include <hip/hip_runtime.h>
#include <cstdint>

// Problem constants
#define NN 8192
#define FF 512
#define FO 64
#define NH 8
#define LDYE 520     // Y row stride: 512 numerator cols + 8 denom cols
#define YPART (8192 * 520)
#define SPLITK 3

// Tiled fp8 layouts (k-major 16-byte granules, staging order), R11: BM=64.
//  Ab: granule G = (rt*512 + k16)*64 + row   (rt: 0..127, 64-row stripes)
//  Vt: granule H = k16*640 + vrow   (vrow: h*64+o; 512+h = e-row; >=520 junk)

typedef __attribute__((ext_vector_type(8))) __bf16 bf16x8;
typedef __attribute__((ext_vector_type(4))) float f32x4;
typedef __attribute__((ext_vector_type(4))) int i32x4;
typedef __attribute__((ext_vector_type(8))) int i32x8;

__device__ __forceinline__ unsigned short f2bf(float f) {
    unsigned int u = __float_as_uint(f);
    u += 0x7fffu + ((u >> 16) & 1u);
    return (unsigned short)(u >> 16);
}

__device__ __forceinline__ void gload16(const void* g, void* l) {
    __builtin_amdgcn_global_load_lds(
        (const __attribute__((address_space(1))) unsigned int*)g,
        (__attribute__((address_space(3))) unsigned int*)l,
        16, 0, 0);
}

// ---------------------------------------------------------------------------
// K0: A fp32 {0.0,1.0} -> fp8 e4m3 (0x00/0x38, exact), tiled for BM=64.
// gid = rt*32768 + k16*64 + row -> Ab[gid*16], fully coalesced writes.
// Each lane reads 64 B dense; a block's 256 lanes span 4 k16 x 64 rows, so
// sibling half-lines are consumed in-block.
// ---------------------------------------------------------------------------
__global__ __launch_bounds__(256) void k_convA8(const float* __restrict__ A,
                                                unsigned char* __restrict__ Ab) {
    const size_t gid = (size_t)blockIdx.x * 256 + threadIdx.x;
    const int row = (int)(gid & 63);
    const int k16 = (int)((gid >> 6) & 511);
    const int rt = (int)(gid >> 15);
    const uint4* src = (const uint4*)(A + (((size_t)(rt * 64 + row)) << 13) + k16 * 16);
    uint4 f0 = src[0], f1 = src[1], f2 = src[2], f3 = src[3];
#define PK8(v) (((v.x >> 22) & 0x38u) | (((v.y >> 22) & 0x38u) << 8) | \
                (((v.z >> 22) & 0x38u) << 16) | (((v.w >> 22) & 0x38u) << 24))
    uint4 o = {PK8(f0), PK8(f1), PK8(f2), PK8(f3)};
#undef PK8
    *(uint4*)(Ab + (gid << 4)) = o;
}

// ---------------------------------------------------------------------------
// K0b: X fp32->bf16; kernels (h,f,o)->Kt (h,o,f) bf16.
// ---------------------------------------------------------------------------
__global__ __launch_bounds__(256) void k_prep(const float* __restrict__ X,
                                              const float* __restrict__ Kw,
                                              unsigned short* __restrict__ Xb,
                                              unsigned short* __restrict__ Ktb) {
    const int b = blockIdx.x;
    const int t = threadIdx.x;
    if (b < 2048) {
        size_t base = ((size_t)b * 256 + t) * 8;
        float4 a = *(const float4*)(X + base);
        float4 c = *(const float4*)(X + base + 4);
        ushort4 o0, o1;
        o0.x = f2bf(a.x); o0.y = f2bf(a.y); o0.z = f2bf(a.z); o0.w = f2bf(a.w);
        o1.x = f2bf(c.x); o1.y = f2bf(c.y); o1.z = f2bf(c.z); o1.w = f2bf(c.w);
        *(ushort4*)(Xb + base) = o0;
        *(ushort4*)(Xb + base + 4) = o1;
    } else {
        int h = b - 2048;
        for (int e = t; e < FF * FO; e += 256) {
            int o = e >> 9, f = e & 511;
            Ktb[(size_t)h * FF * FO + e] = f2bf(Kw[(size_t)h * FF * FO + (size_t)f * FO + o]);
        }
    }
}

// ---------------------------------------------------------------------------
// K1: WX = Xb @ Kt^T bf16 MFMA (K=512), s2 via shfl_xor, e = exp(s2),
// emit fp8 V into tiled Vt (k16-granule layout). Verbatim R7 (512 µs best).
// ---------------------------------------------------------------------------
union WxSmem {
    struct { unsigned short Xs[4096]; unsigned short Ks[2048]; } s;
    unsigned char Vs[64][144];
};

__global__ __launch_bounds__(256) void k_wx(const unsigned short* __restrict__ Xb,
                                            const unsigned short* __restrict__ Ktb,
                                            const float* __restrict__ Aw,
                                            unsigned char* __restrict__ Vt) {
    __shared__ WxSmem sm;
    const int t = threadIdx.x;
    const int n0 = blockIdx.x * 128;
    const int h = blockIdx.y;
    const int lane = t & 63, w = t >> 6;
    const int quad = lane >> 4, l15 = lane & 15;

    const unsigned short* xS0 = Xb + (size_t)(n0 + (t & 127)) * FF + (t >> 7) * 8;
    const unsigned short* xS1 = Xb + (size_t)(n0 + ((t + 256) & 127)) * FF + ((t + 256) >> 7) * 8;
    unsigned short* xD0 = sm.s.Xs + t * 8;
    unsigned short* xD1 = sm.s.Xs + (t + 256) * 8;
    const unsigned short* kS = Ktb + (size_t)h * FF * FO + (size_t)(t & 63) * FF + (t >> 6) * 8;
    unsigned short* kD = sm.s.Ks + t * 8;

    const bf16x8* aF[2];
    const bf16x8* bF[4];
    for (int i = 0; i < 2; ++i)
        aF[i] = (const bf16x8*)(sm.s.Xs + (size_t)(quad * 128 + w * 32 + i * 16 + l15) * 8);
    for (int j = 0; j < 4; ++j)
        bF[j] = (const bf16x8*)(sm.s.Ks + (size_t)(quad * 64 + j * 16 + l15) * 8);

    f32x4 acc[2][4] = {};
    for (int f0 = 0; f0 < FF; f0 += 32) {
        gload16(xS0 + f0, xD0);
        gload16(xS1 + f0, xD1);
        gload16(kS + f0, kD);
        __syncthreads();
        bf16x8 av[2], bv[4];
        for (int i = 0; i < 2; ++i) av[i] = aF[i][0];
        for (int j = 0; j < 4; ++j) bv[j] = bF[j][0];
        for (int i = 0; i < 2; ++i)
            for (int j = 0; j < 4; ++j)
                acc[i][j] = __builtin_amdgcn_mfma_f32_16x16x32_bf16(av[i], bv[j], acc[i][j], 0, 0, 0);
        __syncthreads();
    }

    float a2v[4];
    for (int j = 0; j < 4; ++j) a2v[j] = Aw[h * 128 + 64 + j * 16 + l15];
    float ex[2][4];
    for (int i = 0; i < 2; ++i)
        for (int r = 0; r < 4; ++r) {
            float p = acc[i][0][r] * a2v[0] + acc[i][1][r] * a2v[1]
                    + acc[i][2][r] * a2v[2] + acc[i][3][r] * a2v[3];
            p += __shfl_xor(p, 1);
            p += __shfl_xor(p, 2);
            p += __shfl_xor(p, 4);
            p += __shfl_xor(p, 8);
            ex[i][r] = __expf(p);
        }

    for (int i = 0; i < 2; ++i)
        for (int j = 0; j < 4; ++j) {
            int rowb = w * 32 + i * 16 + quad * 4;
            int col = j * 16 + l15;
            unsigned u = __builtin_amdgcn_cvt_pk_fp8_f32(
                ex[i][0] * acc[i][j][0], ex[i][1] * acc[i][j][1], 0, false);
            u = __builtin_amdgcn_cvt_pk_fp8_f32(
                ex[i][2] * acc[i][j][2], ex[i][3] * acc[i][j][3], (int)u, true);
            *(unsigned*)&sm.Vs[col][rowb] = u;
        }
    __syncthreads();
    for (int j2 = 0; j2 < 2; ++j2) {
        int vid = t + j2 * 256;            // 0..511 = 64 o x 8 k16o (uint4)
        int o = vid >> 3, k16o = vid & 7;
        size_t H = (size_t)((n0 >> 4) + k16o) * 640 + h * 64 + o;
        *(uint4*)(Vt + (H << 4)) = *(const uint4*)&sm.Vs[o][k16o * 16];
    }
    if (l15 == 0) {
        for (int i = 0; i < 2; ++i)
            for (int r = 0; r < 4; ++r) {
                int row = w * 32 + i * 16 + quad * 4 + r;
                unsigned u = __builtin_amdgcn_cvt_pk_fp8_f32(ex[i][r], ex[i][r], 0, false);
                size_t H = (size_t)((n0 >> 4) + (row >> 4)) * 640 + 512 + h;
                Vt[(H << 4) + (row & 15)] = (unsigned char)(u & 0xff);
            }
    }
}

// ---------------------------------------------------------------------------
// K2 (R12): MX-scaled fp8 K=128 MFMA (mfma_scale_f32_16x16x128_f8f6f4,
// scales = e8m0 1.0 => numerically identical to plain fp8, 2.28x matrix rate).
// BK 64->128: 64 iters instead of 128 -> HALF the barrier drains; LDS frag
// reads b64->b128. BM=64, BN=160; wave tile 32x80 -> acc 40 AGPR.
// LDS 28 KB (As 8 KB + Bs 20 KB) -> still 5 blocks/CU LDS-wise.
// av resident (16 VGPR), bv streamed per-j (8) to stay under the
// __launch_bounds__(256,5) ~102-reg cap.
// Per iter: A = exactly 2 gload16/thread (8 KB), B = exactly 5 (20 KB).
// Lane operand layout (16x16x128 fp8): row/col = l&15, k in [(l>>4)*32,+32)
// contiguous = two adjacent k16 granules -> producers (K0, K1) unchanged.
// Grid 128x4x3 = 1536; XCD swizzle keeps 4 ct-friends per A stripe on 1 XCD.
// ---------------------------------------------------------------------------
__global__ __launch_bounds__(256, 5) void k_gemm(const unsigned char* __restrict__ Ab,
                                                 const unsigned char* __restrict__ Vt,
                                                 float* __restrict__ Y) {
    __shared__ unsigned char As[8192];    // kq(8) x row(64) x 16 B
    __shared__ unsigned char Bs[20480];   // kq(8) x n(160) x 16 B
    const int t = threadIdx.x;
    const int id = blockIdx.x;
    const int xcd = id & 7;
    const int u = id >> 3;                 // 0..191
    const int ct = u & 3;
    const int rp = ((u >> 2) << 3) | xcd;  // 0..383
    const int rt = rp & 127;               // 0..127
    const int part = rp >> 7;              // 0..2
    const int ks0 = (part * 64) / SPLITK;  // 64 iters of BK=128 total
    const int ks1 = ((part + 1) * 64) / SPLITK;

    // A staging: 2 gload16 cover the 8 KB tile (granules t and t+256).
    const unsigned char* aS = Ab + ((size_t)rt << 19) + (size_t)t * 16;
    unsigned char* aD0 = As + t * 16;
    unsigned char* aD1 = As + t * 16 + 4096;
    // B staging: granule g = t + 256j; kq = g/160, n = g%160.
    const unsigned char* bS[5];
    unsigned char* bD[5];
#pragma unroll
    for (int j = 0; j < 5; ++j) {
        int g = t + 256 * j;
        bS[j] = Vt + (size_t)((g / 160) * 640 + ct * 160 + (g % 160)) * 16;
        bD[j] = Bs + g * 16;
    }

    const int lane = t & 63;
    const int w = t >> 6;
    const int wm = w >> 1, wn = w & 1;
    const int quad = lane >> 4, l15 = lane & 15;

    // fragment byte offsets: lane's 32 k-bytes = granules kq=quad*2, quad*2+1
    int aOff[2], bOff[5];
#pragma unroll
    for (int i = 0; i < 2; ++i)
        aOff[i] = quad * 2048 + (wm * 32 + i * 16 + l15) * 16;
#pragma unroll
    for (int j = 0; j < 5; ++j)
        bOff[j] = quad * 5120 + (wn * 80 + j * 16 + l15) * 16;

    f32x4 acc[2][5] = {};

    for (int ks = ks0; ks < ks1; ++ks) {
        const size_t koA = (size_t)ks << 13;       // *8192
        const size_t koB = (size_t)ks * 81920;     // *8*640*16
        gload16(aS + koA, aD0);
        gload16(aS + koA + 4096, aD1);
#pragma unroll
        for (int j = 0; j < 5; ++j) gload16(bS[j] + koB, bD[j]);
        __syncthreads();
        i32x8 av[2];
#pragma unroll
        for (int i = 0; i < 2; ++i) {
            i32x4 lo = *(const i32x4*)(As + aOff[i]);
            i32x4 hi = *(const i32x4*)(As + aOff[i] + 1024);
            av[i] = __builtin_shufflevector(lo, hi, 0, 1, 2, 3, 4, 5, 6, 7);
        }
#pragma unroll
        for (int j = 0; j < 5; ++j) {
            i32x4 lo = *(const i32x4*)(Bs + bOff[j]);
            i32x4 hi = *(const i32x4*)(Bs + bOff[j] + 2560);
            i32x8 bv = __builtin_shufflevector(lo, hi, 0, 1, 2, 3, 4, 5, 6, 7);
            acc[0][j] = __builtin_amdgcn_mfma_scale_f32_16x16x128_f8f6f4(
                av[0], bv, acc[0][j], 0, 0, 0, 0x7f7f7f7f, 0, 0x7f7f7f7f);
            acc[1][j] = __builtin_amdgcn_mfma_scale_f32_16x16x128_f8f6f4(
                av[1], bv, acc[1][j], 0, 0, 0, 0x7f7f7f7f, 0, 0x7f7f7f7f);
        }
        __syncthreads();
    }

    // C/D layout: col = lane&15, row = (lane>>4)*4 + reg
    float* Yp = Y + (size_t)part * YPART;
    for (int i = 0; i < 2; ++i) {
        int row = rt * 64 + wm * 32 + i * 16 + quad * 4;
        for (int j = 0; j < 5; ++j) {
            int col = ct * 160 + wn * 80 + j * 16 + l15;
            if (col < 520) {
                for (int r = 0; r < 4; ++r)
                    Yp[(size_t)(row + r) * LDYE + col] = acc[i][j][r];
            }
        }
    }
}

// ---------------------------------------------------------------------------
// K3: out[n, h*64+o] = relu( sum_p Ynum / sum_p Yden )
// ---------------------------------------------------------------------------
__global__ __launch_bounds__(256) void k_epi(const float* __restrict__ Y,
                                             float* __restrict__ out) {
    int idx = blockIdx.x * 256 + threadIdx.x;
    int n = idx >> 7;
    int c = (idx & 127) * 4;
    int h = c >> 6;
    float4 u = {0.f, 0.f, 0.f, 0.f};
    float den = 0.f;
    const float* yp = Y + (size_t)n * LDYE;
#pragma unroll
    for (int p = 0; p < SPLITK; ++p) {
        float4 v = *(const float4*)(yp + c);
        u.x += v.x; u.y += v.y; u.z += v.z; u.w += v.w;
        den += yp[512 + h];
        yp += (size_t)YPART;
    }
    float inv = 1.0f / den;
    float4 o;
    o.x = fmaxf(u.x * inv, 0.f);
    o.y = fmaxf(u.y * inv, 0.f);
    o.z = fmaxf(u.z * inv, 0.f);
    o.w = fmaxf(u.w * inv, 0.f);
    *(float4*)(out + (size_t)n * 512 + c) = o;
}

extern "C" void kernel_launch(void* const* d_in, const int* in_sizes, int n_in,
                              void* d_out, int out_size, void* d_ws, size_t ws_size,
                              hipStream_t stream) {
    const float* X  = (const float*)d_in[0];   // (8192, 512)
    const float* A  = (const float*)d_in[1];   // (8192, 8192)
    const float* Kw = (const float*)d_in[2];   // (8, 512, 64)
    const float* Aw = (const float*)d_in[3];   // (8, 128)
    float* out = (float*)d_out;                // (8192, 512)
    char* ws = (char*)d_ws;
    // ws: Ab 64 MiB | Vt 5 MiB | Yb 3*16.25 MiB (~118 MiB).
    // Xb (8 MiB) + Ktb (0.5 MiB) alias the head of Yb (consumed by k_wx
    // before k_gemm writes Yb).
    unsigned char* Ab = (unsigned char*)ws;
    unsigned char* Vt = (unsigned char*)(ws + (size_t)67108864);
    float* Yb = (float*)(ws + (size_t)67108864 + (size_t)5242880);
    unsigned short* Xb = (unsigned short*)Yb;
    unsigned short* Ktb = Xb + (size_t)NN * FF;

    k_convA8<<<dim3(16384), dim3(256), 0, stream>>>(A, Ab);
    k_prep<<<dim3(2056), dim3(256), 0, stream>>>(X, Kw, Xb, Ktb);
    k_wx<<<dim3(64, 8), dim3(256), 0, stream>>>(Xb, Ktb, Aw, Vt);
    k_gemm<<<dim3(1536), dim3(256), 0, stream>>>(Ab, Vt, Yb);
    k_epi<<<dim3(4096), dim3(256), 0, stream>>>(Yb, out);
}

// Round 2
// 486.819 us; speedup vs baseline: 1.0461x; 1.0344x over previous
//
#include <hip/hip_runtime.h>
#include <cstdint>

// Problem constants
#define NN 8192
#define FF 512
#define FO 64
#define NH 8
#define LDYE 520     // Y row stride: 512 numerator cols + 8 denom cols
#define YPART (8192 * 520)
#define SPLITK 3

// Tiled fp8 layouts (k-major 16-byte granules, staging order), R11: BM=64.
//  Ab: granule G = (rt*512 + k16)*64 + row   (rt: 0..127, 64-row stripes)
//  Vt: granule H = k16*640 + vrow   (vrow: h*64+o; 512+h = e-row; >=520 junk)

typedef __attribute__((ext_vector_type(8))) __bf16 bf16x8;
typedef __attribute__((ext_vector_type(4))) float f32x4;
typedef __attribute__((ext_vector_type(4))) int i32x4;
typedef __attribute__((ext_vector_type(8))) int i32x8;

__device__ __forceinline__ unsigned short f2bf(float f) {
    unsigned int u = __float_as_uint(f);
    u += 0x7fffu + ((u >> 16) & 1u);
    return (unsigned short)(u >> 16);
}

__device__ __forceinline__ void gload16(const void* g, void* l) {
    __builtin_amdgcn_global_load_lds(
        (const __attribute__((address_space(1))) unsigned int*)g,
        (__attribute__((address_space(3))) unsigned int*)l,
        16, 0, 0);
}

// ---------------------------------------------------------------------------
// K0 (R13): A fp32 {0.0,1.0} -> fp8 e4m3 (0x00/0x38, exact), tiled output,
// COALESCED both sides via LDS transpose.
// Old version: each lane read 64 B at 32 KB inter-lane stride -> every load
// touched 64 scattered cache lines (suspected ~3x off BW roofline).
// New: block = 64 rows x 256 cols of A. Reads: wave-contiguous 1 KB per row
// segment (16 passes of 4 rows x 1 KB). Convert in-reg, stage in padded LDS
// [64][272] (write side 2-way free; read side = 1KB/32-bank floor), then the
// output tile (k16=cb*16..+15, rows 0..63) is ONE contiguous 16 KB region:
// granule (rt*512 + cb*16 + k16l)*64 + row, k16l-major over rows.
// ---------------------------------------------------------------------------
__global__ __launch_bounds__(256) void k_convA8(const float* __restrict__ A,
                                                unsigned char* __restrict__ Ab) {
    __shared__ unsigned char Ls[64][272];   // 64 rows x 256 fp8 bytes, +16 pad
    const int t = threadIdx.x;
    const int rt = blockIdx.x >> 5;         // 0..127  (row stripe of 64)
    const int cb = blockIdx.x & 31;         // 0..31   (column block of 256)
    const float* src = A + ((size_t)rt << 19) + ((size_t)cb << 8);
#pragma unroll
    for (int p = 0; p < 16; ++p) {
        int row = p * 4 + (t >> 6);
        int col = (t & 63) * 4;
        uint4 v = *(const uint4*)(src + ((size_t)row << 13) + col);
        unsigned o = ((v.x >> 22) & 0x38u) | (((v.y >> 22) & 0x38u) << 8) |
                     (((v.z >> 22) & 0x38u) << 16) | (((v.w >> 22) & 0x38u) << 24);
        *(unsigned*)&Ls[row][col] = o;
    }
    __syncthreads();
    unsigned char* dst = Ab + (((size_t)rt * 512 + (size_t)cb * 16) << 10);
#pragma unroll
    for (int j = 0; j < 4; ++j) {
        int g = t + 256 * j;                // 0..1023 = k16l(16) x row(64)
        int row = g & 63, k16l = g >> 6;
        *(uint4*)(dst + ((size_t)g << 4)) = *(const uint4*)&Ls[row][k16l * 16];
    }
}

// ---------------------------------------------------------------------------
// K0b: X fp32->bf16; kernels (h,f,o)->Kt (h,o,f) bf16.
// ---------------------------------------------------------------------------
__global__ __launch_bounds__(256) void k_prep(const float* __restrict__ X,
                                              const float* __restrict__ Kw,
                                              unsigned short* __restrict__ Xb,
                                              unsigned short* __restrict__ Ktb) {
    const int b = blockIdx.x;
    const int t = threadIdx.x;
    if (b < 2048) {
        size_t base = ((size_t)b * 256 + t) * 8;
        float4 a = *(const float4*)(X + base);
        float4 c = *(const float4*)(X + base + 4);
        ushort4 o0, o1;
        o0.x = f2bf(a.x); o0.y = f2bf(a.y); o0.z = f2bf(a.z); o0.w = f2bf(a.w);
        o1.x = f2bf(c.x); o1.y = f2bf(c.y); o1.z = f2bf(c.z); o1.w = f2bf(c.w);
        *(ushort4*)(Xb + base) = o0;
        *(ushort4*)(Xb + base + 4) = o1;
    } else {
        int h = b - 2048;
        for (int e = t; e < FF * FO; e += 256) {
            int o = e >> 9, f = e & 511;
            Ktb[(size_t)h * FF * FO + e] = f2bf(Kw[(size_t)h * FF * FO + (size_t)f * FO + o]);
        }
    }
}

// ---------------------------------------------------------------------------
// K1: WX = Xb @ Kt^T bf16 MFMA (K=512), s2 via shfl_xor, e = exp(s2),
// emit fp8 V into tiled Vt (k16-granule layout). Verbatim R7 (512 µs best).
// ---------------------------------------------------------------------------
union WxSmem {
    struct { unsigned short Xs[4096]; unsigned short Ks[2048]; } s;
    unsigned char Vs[64][144];
};

__global__ __launch_bounds__(256) void k_wx(const unsigned short* __restrict__ Xb,
                                            const unsigned short* __restrict__ Ktb,
                                            const float* __restrict__ Aw,
                                            unsigned char* __restrict__ Vt) {
    __shared__ WxSmem sm;
    const int t = threadIdx.x;
    const int n0 = blockIdx.x * 128;
    const int h = blockIdx.y;
    const int lane = t & 63, w = t >> 6;
    const int quad = lane >> 4, l15 = lane & 15;

    const unsigned short* xS0 = Xb + (size_t)(n0 + (t & 127)) * FF + (t >> 7) * 8;
    const unsigned short* xS1 = Xb + (size_t)(n0 + ((t + 256) & 127)) * FF + ((t + 256) >> 7) * 8;
    unsigned short* xD0 = sm.s.Xs + t * 8;
    unsigned short* xD1 = sm.s.Xs + (t + 256) * 8;
    const unsigned short* kS = Ktb + (size_t)h * FF * FO + (size_t)(t & 63) * FF + (t >> 6) * 8;
    unsigned short* kD = sm.s.Ks + t * 8;

    const bf16x8* aF[2];
    const bf16x8* bF[4];
    for (int i = 0; i < 2; ++i)
        aF[i] = (const bf16x8*)(sm.s.Xs + (size_t)(quad * 128 + w * 32 + i * 16 + l15) * 8);
    for (int j = 0; j < 4; ++j)
        bF[j] = (const bf16x8*)(sm.s.Ks + (size_t)(quad * 64 + j * 16 + l15) * 8);

    f32x4 acc[2][4] = {};
    for (int f0 = 0; f0 < FF; f0 += 32) {
        gload16(xS0 + f0, xD0);
        gload16(xS1 + f0, xD1);
        gload16(kS + f0, kD);
        __syncthreads();
        bf16x8 av[2], bv[4];
        for (int i = 0; i < 2; ++i) av[i] = aF[i][0];
        for (int j = 0; j < 4; ++j) bv[j] = bF[j][0];
        for (int i = 0; i < 2; ++i)
            for (int j = 0; j < 4; ++j)
                acc[i][j] = __builtin_amdgcn_mfma_f32_16x16x32_bf16(av[i], bv[j], acc[i][j], 0, 0, 0);
        __syncthreads();
    }

    float a2v[4];
    for (int j = 0; j < 4; ++j) a2v[j] = Aw[h * 128 + 64 + j * 16 + l15];
    float ex[2][4];
    for (int i = 0; i < 2; ++i)
        for (int r = 0; r < 4; ++r) {
            float p = acc[i][0][r] * a2v[0] + acc[i][1][r] * a2v[1]
                    + acc[i][2][r] * a2v[2] + acc[i][3][r] * a2v[3];
            p += __shfl_xor(p, 1);
            p += __shfl_xor(p, 2);
            p += __shfl_xor(p, 4);
            p += __shfl_xor(p, 8);
            ex[i][r] = __expf(p);
        }

    for (int i = 0; i < 2; ++i)
        for (int j = 0; j < 4; ++j) {
            int rowb = w * 32 + i * 16 + quad * 4;
            int col = j * 16 + l15;
            unsigned u = __builtin_amdgcn_cvt_pk_fp8_f32(
                ex[i][0] * acc[i][j][0], ex[i][1] * acc[i][j][1], 0, false);
            u = __builtin_amdgcn_cvt_pk_fp8_f32(
                ex[i][2] * acc[i][j][2], ex[i][3] * acc[i][j][3], (int)u, true);
            *(unsigned*)&sm.Vs[col][rowb] = u;
        }
    __syncthreads();
    for (int j2 = 0; j2 < 2; ++j2) {
        int vid = t + j2 * 256;            // 0..511 = 64 o x 8 k16o (uint4)
        int o = vid >> 3, k16o = vid & 7;
        size_t H = (size_t)((n0 >> 4) + k16o) * 640 + h * 64 + o;
        *(uint4*)(Vt + (H << 4)) = *(const uint4*)&sm.Vs[o][k16o * 16];
    }
    if (l15 == 0) {
        for (int i = 0; i < 2; ++i)
            for (int r = 0; r < 4; ++r) {
                int row = w * 32 + i * 16 + quad * 4 + r;
                unsigned u = __builtin_amdgcn_cvt_pk_fp8_f32(ex[i][r], ex[i][r], 0, false);
                size_t H = (size_t)((n0 >> 4) + (row >> 4)) * 640 + 512 + h;
                Vt[(H << 4) + (row & 15)] = (unsigned char)(u & 0xff);
            }
    }
}

// ---------------------------------------------------------------------------
// K2 (R12): MX-scaled fp8 K=128 MFMA (mfma_scale_f32_16x16x128_f8f6f4,
// scales = e8m0 1.0 => numerically identical to plain fp8, 2.28x matrix rate).
// BK=128: 64 iters; BM=64, BN=160; wave tile 32x80 -> acc 40 AGPR.
// LDS 28 KB (As 8 KB + Bs 20 KB). av resident, bv streamed per-j.
// Per iter: A = exactly 2 gload16/thread (8 KB), B = exactly 5 (20 KB).
// Lane operand layout (16x16x128 fp8): row/col = l&15, k in [(l>>4)*32,+32)
// contiguous = two adjacent k16 granules -> producers (K0, K1) unchanged.
// Grid 128x4x3 = 1536; XCD swizzle keeps 4 ct-friends per A stripe on 1 XCD.
// ---------------------------------------------------------------------------
__global__ __launch_bounds__(256, 5) void k_gemm(const unsigned char* __restrict__ Ab,
                                                 const unsigned char* __restrict__ Vt,
                                                 float* __restrict__ Y) {
    __shared__ unsigned char As[8192];    // kq(8) x row(64) x 16 B
    __shared__ unsigned char Bs[20480];   // kq(8) x n(160) x 16 B
    const int t = threadIdx.x;
    const int id = blockIdx.x;
    const int xcd = id & 7;
    const int u = id >> 3;                 // 0..191
    const int ct = u & 3;
    const int rp = ((u >> 2) << 3) | xcd;  // 0..383
    const int rt = rp & 127;               // 0..127
    const int part = rp >> 7;              // 0..2
    const int ks0 = (part * 64) / SPLITK;  // 64 iters of BK=128 total
    const int ks1 = ((part + 1) * 64) / SPLITK;

    // A staging: 2 gload16 cover the 8 KB tile (granules t and t+256).
    const unsigned char* aS = Ab + ((size_t)rt << 19) + (size_t)t * 16;
    unsigned char* aD0 = As + t * 16;
    unsigned char* aD1 = As + t * 16 + 4096;
    // B staging: granule g = t + 256j; kq = g/160, n = g%160.
    const unsigned char* bS[5];
    unsigned char* bD[5];
#pragma unroll
    for (int j = 0; j < 5; ++j) {
        int g = t + 256 * j;
        bS[j] = Vt + (size_t)((g / 160) * 640 + ct * 160 + (g % 160)) * 16;
        bD[j] = Bs + g * 16;
    }

    const int lane = t & 63;
    const int w = t >> 6;
    const int wm = w >> 1, wn = w & 1;
    const int quad = lane >> 4, l15 = lane & 15;

    // fragment byte offsets: lane's 32 k-bytes = granules kq=quad*2, quad*2+1
    int aOff[2], bOff[5];
#pragma unroll
    for (int i = 0; i < 2; ++i)
        aOff[i] = quad * 2048 + (wm * 32 + i * 16 + l15) * 16;
#pragma unroll
    for (int j = 0; j < 5; ++j)
        bOff[j] = quad * 5120 + (wn * 80 + j * 16 + l15) * 16;

    f32x4 acc[2][5] = {};

    for (int ks = ks0; ks < ks1; ++ks) {
        const size_t koA = (size_t)ks << 13;       // *8192
        const size_t koB = (size_t)ks * 81920;     // *8*640*16
        gload16(aS + koA, aD0);
        gload16(aS + koA + 4096, aD1);
#pragma unroll
        for (int j = 0; j < 5; ++j) gload16(bS[j] + koB, bD[j]);
        __syncthreads();
        i32x8 av[2];
#pragma unroll
        for (int i = 0; i < 2; ++i) {
            i32x4 lo = *(const i32x4*)(As + aOff[i]);
            i32x4 hi = *(const i32x4*)(As + aOff[i] + 1024);
            av[i] = __builtin_shufflevector(lo, hi, 0, 1, 2, 3, 4, 5, 6, 7);
        }
#pragma unroll
        for (int j = 0; j < 5; ++j) {
            i32x4 lo = *(const i32x4*)(Bs + bOff[j]);
            i32x4 hi = *(const i32x4*)(Bs + bOff[j] + 2560);
            i32x8 bv = __builtin_shufflevector(lo, hi, 0, 1, 2, 3, 4, 5, 6, 7);
            acc[0][j] = __builtin_amdgcn_mfma_scale_f32_16x16x128_f8f6f4(
                av[0], bv, acc[0][j], 0, 0, 0, 0x7f7f7f7f, 0, 0x7f7f7f7f);
            acc[1][j] = __builtin_amdgcn_mfma_scale_f32_16x16x128_f8f6f4(
                av[1], bv, acc[1][j], 0, 0, 0, 0x7f7f7f7f, 0, 0x7f7f7f7f);
        }
        __syncthreads();
    }

    // C/D layout: col = lane&15, row = (lane>>4)*4 + reg
    float* Yp = Y + (size_t)part * YPART;
    for (int i = 0; i < 2; ++i) {
        int row = rt * 64 + wm * 32 + i * 16 + quad * 4;
        for (int j = 0; j < 5; ++j) {
            int col = ct * 160 + wn * 80 + j * 16 + l15;
            if (col < 520) {
                for (int r = 0; r < 4; ++r)
                    Yp[(size_t)(row + r) * LDYE + col] = acc[i][j][r];
            }
        }
    }
}

// ---------------------------------------------------------------------------
// K3: out[n, h*64+o] = relu( sum_p Ynum / sum_p Yden )
// ---------------------------------------------------------------------------
__global__ __launch_bounds__(256) void k_epi(const float* __restrict__ Y,
                                             float* __restrict__ out) {
    int idx = blockIdx.x * 256 + threadIdx.x;
    int n = idx >> 7;
    int c = (idx & 127) * 4;
    int h = c >> 6;
    float4 u = {0.f, 0.f, 0.f, 0.f};
    float den = 0.f;
    const float* yp = Y + (size_t)n * LDYE;
#pragma unroll
    for (int p = 0; p < SPLITK; ++p) {
        float4 v = *(const float4*)(yp + c);
        u.x += v.x; u.y += v.y; u.z += v.z; u.w += v.w;
        den += yp[512 + h];
        yp += (size_t)YPART;
    }
    float inv = 1.0f / den;
    float4 o;
    o.x = fmaxf(u.x * inv, 0.f);
    o.y = fmaxf(u.y * inv, 0.f);
    o.z = fmaxf(u.z * inv, 0.f);
    o.w = fmaxf(u.w * inv, 0.f);
    *(float4*)(out + (size_t)n * 512 + c) = o;
}

extern "C" void kernel_launch(void* const* d_in, const int* in_sizes, int n_in,
                              void* d_out, int out_size, void* d_ws, size_t ws_size,
                              hipStream_t stream) {
    const float* X  = (const float*)d_in[0];   // (8192, 512)
    const float* A  = (const float*)d_in[1];   // (8192, 8192)
    const float* Kw = (const float*)d_in[2];   // (8, 512, 64)
    const float* Aw = (const float*)d_in[3];   // (8, 128)
    float* out = (float*)d_out;                // (8192, 512)
    char* ws = (char*)d_ws;
    // ws: Ab 64 MiB | Vt 5 MiB | Yb 3*16.25 MiB (~118 MiB).
    // Xb (8 MiB) + Ktb (0.5 MiB) alias the head of Yb (consumed by k_wx
    // before k_gemm writes Yb).
    unsigned char* Ab = (unsigned char*)ws;
    unsigned char* Vt = (unsigned char*)(ws + (size_t)67108864);
    float* Yb = (float*)(ws + (size_t)67108864 + (size_t)5242880);
    unsigned short* Xb = (unsigned short*)Yb;
    unsigned short* Ktb = Xb + (size_t)NN * FF;

    k_convA8<<<dim3(4096), dim3(256), 0, stream>>>(A, Ab);
    k_prep<<<dim3(2056), dim3(256), 0, stream>>>(X, Kw, Xb, Ktb);
    k_wx<<<dim3(64, 8), dim3(256), 0, stream>>>(Xb, Ktb, Aw, Vt);
    k_gemm<<<dim3(1536), dim3(256), 0, stream>>>(Ab, Vt, Yb);
    k_epi<<<dim3(4096), dim3(256), 0, stream>>>(Yb, out);
}

// Round 3
// 478.290 us; speedup vs baseline: 1.0648x; 1.0178x over previous
//
#include <hip/hip_runtime.h>
#include <cstdint>

// Problem constants
#define NN 8192
#define FF 512
#define FO 64
#define NH 8
#define LDYE 520     // Y row stride: 512 numerator cols + 8 denom cols
#define YPART (8192 * 520)
#define SPLITK 2

// Tiled fp8 layouts (k-major 16-byte granules, staging order).
//  Ab: granule G = (rt*512 + k16)*64 + row   (rt: 0..127, 64-row stripes)
//  Vt: granule H = k16*640 + vrow   (vrow: h*64+o; 512+h = e-row; >=520 junk)

typedef __attribute__((ext_vector_type(8))) __bf16 bf16x8;
typedef __attribute__((ext_vector_type(4))) float f32x4;
typedef __attribute__((ext_vector_type(4))) int i32x4;
typedef __attribute__((ext_vector_type(8))) int i32x8;

__device__ __forceinline__ unsigned short f2bf(float f) {
    unsigned int u = __float_as_uint(f);
    u += 0x7fffu + ((u >> 16) & 1u);
    return (unsigned short)(u >> 16);
}

__device__ __forceinline__ void gload16(const void* g, void* l) {
    __builtin_amdgcn_global_load_lds(
        (const __attribute__((address_space(1))) unsigned int*)g,
        (__attribute__((address_space(3))) unsigned int*)l,
        16, 0, 0);
}

// ---------------------------------------------------------------------------
// K0 (R13): A fp32 {0.0,1.0} -> fp8 e4m3 (0x00/0x38, exact), tiled output,
// coalesced both sides via LDS transpose. At BW roofline (~53 us).
// ---------------------------------------------------------------------------
__global__ __launch_bounds__(256) void k_convA8(const float* __restrict__ A,
                                                unsigned char* __restrict__ Ab) {
    __shared__ unsigned char Ls[64][272];   // 64 rows x 256 fp8 bytes, +16 pad
    const int t = threadIdx.x;
    const int rt = blockIdx.x >> 5;         // 0..127  (row stripe of 64)
    const int cb = blockIdx.x & 31;         // 0..31   (column block of 256)
    const float* src = A + ((size_t)rt << 19) + ((size_t)cb << 8);
#pragma unroll
    for (int p = 0; p < 16; ++p) {
        int row = p * 4 + (t >> 6);
        int col = (t & 63) * 4;
        uint4 v = *(const uint4*)(src + ((size_t)row << 13) + col);
        unsigned o = ((v.x >> 22) & 0x38u) | (((v.y >> 22) & 0x38u) << 8) |
                     (((v.z >> 22) & 0x38u) << 16) | (((v.w >> 22) & 0x38u) << 24);
        *(unsigned*)&Ls[row][col] = o;
    }
    __syncthreads();
    unsigned char* dst = Ab + (((size_t)rt * 512 + (size_t)cb * 16) << 10);
#pragma unroll
    for (int j = 0; j < 4; ++j) {
        int g = t + 256 * j;                // 0..1023 = k16l(16) x row(64)
        int row = g & 63, k16l = g >> 6;
        *(uint4*)(dst + ((size_t)g << 4)) = *(const uint4*)&Ls[row][k16l * 16];
    }
}

// ---------------------------------------------------------------------------
// K0b: X fp32->bf16; kernels (h,f,o)->Kt (h,o,f) bf16.
// ---------------------------------------------------------------------------
__global__ __launch_bounds__(256) void k_prep(const float* __restrict__ X,
                                              const float* __restrict__ Kw,
                                              unsigned short* __restrict__ Xb,
                                              unsigned short* __restrict__ Ktb) {
    const int b = blockIdx.x;
    const int t = threadIdx.x;
    if (b < 2048) {
        size_t base = ((size_t)b * 256 + t) * 8;
        float4 a = *(const float4*)(X + base);
        float4 c = *(const float4*)(X + base + 4);
        ushort4 o0, o1;
        o0.x = f2bf(a.x); o0.y = f2bf(a.y); o0.z = f2bf(a.z); o0.w = f2bf(a.w);
        o1.x = f2bf(c.x); o1.y = f2bf(c.y); o1.z = f2bf(c.z); o1.w = f2bf(c.w);
        *(ushort4*)(Xb + base) = o0;
        *(ushort4*)(Xb + base + 4) = o1;
    } else {
        int h = b - 2048;
        for (int e = t; e < FF * FO; e += 256) {
            int o = e >> 9, f = e & 511;
            Ktb[(size_t)h * FF * FO + e] = f2bf(Kw[(size_t)h * FF * FO + (size_t)f * FO + o]);
        }
    }
}

// ---------------------------------------------------------------------------
// K1: WX = Xb @ Kt^T bf16 MFMA (K=512), s2 via shfl_xor, e = exp(s2),
// emit fp8 V into tiled Vt (k16-granule layout). Verbatim R7.
// ---------------------------------------------------------------------------
union WxSmem {
    struct { unsigned short Xs[4096]; unsigned short Ks[2048]; } s;
    unsigned char Vs[64][144];
};

__global__ __launch_bounds__(256) void k_wx(const unsigned short* __restrict__ Xb,
                                            const unsigned short* __restrict__ Ktb,
                                            const float* __restrict__ Aw,
                                            unsigned char* __restrict__ Vt) {
    __shared__ WxSmem sm;
    const int t = threadIdx.x;
    const int n0 = blockIdx.x * 128;
    const int h = blockIdx.y;
    const int lane = t & 63, w = t >> 6;
    const int quad = lane >> 4, l15 = lane & 15;

    const unsigned short* xS0 = Xb + (size_t)(n0 + (t & 127)) * FF + (t >> 7) * 8;
    const unsigned short* xS1 = Xb + (size_t)(n0 + ((t + 256) & 127)) * FF + ((t + 256) >> 7) * 8;
    unsigned short* xD0 = sm.s.Xs + t * 8;
    unsigned short* xD1 = sm.s.Xs + (t + 256) * 8;
    const unsigned short* kS = Ktb + (size_t)h * FF * FO + (size_t)(t & 63) * FF + (t >> 6) * 8;
    unsigned short* kD = sm.s.Ks + t * 8;

    const bf16x8* aF[2];
    const bf16x8* bF[4];
    for (int i = 0; i < 2; ++i)
        aF[i] = (const bf16x8*)(sm.s.Xs + (size_t)(quad * 128 + w * 32 + i * 16 + l15) * 8);
    for (int j = 0; j < 4; ++j)
        bF[j] = (const bf16x8*)(sm.s.Ks + (size_t)(quad * 64 + j * 16 + l15) * 8);

    f32x4 acc[2][4] = {};
    for (int f0 = 0; f0 < FF; f0 += 32) {
        gload16(xS0 + f0, xD0);
        gload16(xS1 + f0, xD1);
        gload16(kS + f0, kD);
        __syncthreads();
        bf16x8 av[2], bv[4];
        for (int i = 0; i < 2; ++i) av[i] = aF[i][0];
        for (int j = 0; j < 4; ++j) bv[j] = bF[j][0];
        for (int i = 0; i < 2; ++i)
            for (int j = 0; j < 4; ++j)
                acc[i][j] = __builtin_amdgcn_mfma_f32_16x16x32_bf16(av[i], bv[j], acc[i][j], 0, 0, 0);
        __syncthreads();
    }

    float a2v[4];
    for (int j = 0; j < 4; ++j) a2v[j] = Aw[h * 128 + 64 + j * 16 + l15];
    float ex[2][4];
    for (int i = 0; i < 2; ++i)
        for (int r = 0; r < 4; ++r) {
            float p = acc[i][0][r] * a2v[0] + acc[i][1][r] * a2v[1]
                    + acc[i][2][r] * a2v[2] + acc[i][3][r] * a2v[3];
            p += __shfl_xor(p, 1);
            p += __shfl_xor(p, 2);
            p += __shfl_xor(p, 4);
            p += __shfl_xor(p, 8);
            ex[i][r] = __expf(p);
        }

    for (int i = 0; i < 2; ++i)
        for (int j = 0; j < 4; ++j) {
            int rowb = w * 32 + i * 16 + quad * 4;
            int col = j * 16 + l15;
            unsigned u = __builtin_amdgcn_cvt_pk_fp8_f32(
                ex[i][0] * acc[i][j][0], ex[i][1] * acc[i][j][1], 0, false);
            u = __builtin_amdgcn_cvt_pk_fp8_f32(
                ex[i][2] * acc[i][j][2], ex[i][3] * acc[i][j][3], (int)u, true);
            *(unsigned*)&sm.Vs[col][rowb] = u;
        }
    __syncthreads();
    for (int j2 = 0; j2 < 2; ++j2) {
        int vid = t + j2 * 256;            // 0..511 = 64 o x 8 k16o (uint4)
        int o = vid >> 3, k16o = vid & 7;
        size_t H = (size_t)((n0 >> 4) + k16o) * 640 + h * 64 + o;
        *(uint4*)(Vt + (H << 4)) = *(const uint4*)&sm.Vs[o][k16o * 16];
    }
    if (l15 == 0) {
        for (int i = 0; i < 2; ++i)
            for (int r = 0; r < 4; ++r) {
                int row = w * 32 + i * 16 + quad * 4 + r;
                unsigned u = __builtin_amdgcn_cvt_pk_fp8_f32(ex[i][r], ex[i][r], 0, false);
                size_t H = (size_t)((n0 >> 4) + (row >> 4)) * 640 + 512 + h;
                Vt[(H << 4) + (row & 15)] = (unsigned char)(u & 0xff);
            }
    }
}

// ---------------------------------------------------------------------------
// K2 (R14): MX-scaled fp8 K=128 MFMA; geometry retiled for EXACT residency.
// BM=64, BN=128 (5 ct over N=640), SPLITK=2 -> grid 128*5*2 = 1280 blocks
// = exactly 5/CU, matching the 5-resident cap (LDS 24 KB, (256,5) regs).
// Kills the 6-on-5 straggler wave of the old 1536-block grid (~1-block/CU
// second wave at ~20% machine util = the rate-/barrier-invariant stall).
// Uniform 32 iters/block. acc 2x4 (32 AGPR); B staging exactly 4 gload16.
// ---------------------------------------------------------------------------
__global__ __launch_bounds__(256, 5) void k_gemm(const unsigned char* __restrict__ Ab,
                                                 const unsigned char* __restrict__ Vt,
                                                 float* __restrict__ Y) {
    __shared__ unsigned char As[8192];    // kq(8) x row(64) x 16 B
    __shared__ unsigned char Bs[16384];   // kq(8) x n(128) x 16 B
    const int t = threadIdx.x;
    const int id = blockIdx.x;
    const int xcd = id & 7;
    const int u = id >> 3;                 // 0..159
    const int ct = u % 5;                  // 0..4
    const int rp = (u / 5) * 8 + xcd;      // 0..255
    const int rt = rp & 127;               // 0..127
    const int part = rp >> 7;              // 0..1
    const int ks0 = part * 32;             // 64 iters of BK=128 total
    const int ks1 = ks0 + 32;

    // A staging: 2 gload16 cover the 8 KB tile (granules t and t+256).
    const unsigned char* aS = Ab + ((size_t)rt << 19) + (size_t)t * 16;
    unsigned char* aD0 = As + t * 16;
    unsigned char* aD1 = As + t * 16 + 4096;
    // B staging: granule g = t + 256j (0..1023); kq = g>>7, n = g&127.
    const unsigned char* bS[4];
    unsigned char* bD[4];
#pragma unroll
    for (int j = 0; j < 4; ++j) {
        int g = t + 256 * j;
        bS[j] = Vt + (size_t)((g >> 7) * 640 + ct * 128 + (g & 127)) * 16;
        bD[j] = Bs + g * 16;
    }

    const int lane = t & 63;
    const int w = t >> 6;
    const int wm = w >> 1, wn = w & 1;
    const int quad = lane >> 4, l15 = lane & 15;

    // fragment byte offsets: lane's 32 k-bytes = granules kq=quad*2, quad*2+1
    int aOff[2], bOff[4];
#pragma unroll
    for (int i = 0; i < 2; ++i)
        aOff[i] = quad * 2048 + (wm * 32 + i * 16 + l15) * 16;
#pragma unroll
    for (int j = 0; j < 4; ++j)
        bOff[j] = quad * 4096 + (wn * 64 + j * 16 + l15) * 16;

    f32x4 acc[2][4] = {};

    for (int ks = ks0; ks < ks1; ++ks) {
        const size_t koA = (size_t)ks << 13;       // *8192
        const size_t koB = (size_t)ks * 81920;     // *8*640*16
        gload16(aS + koA, aD0);
        gload16(aS + koA + 4096, aD1);
#pragma unroll
        for (int j = 0; j < 4; ++j) gload16(bS[j] + koB, bD[j]);
        __syncthreads();
        i32x8 av[2];
#pragma unroll
        for (int i = 0; i < 2; ++i) {
            i32x4 lo = *(const i32x4*)(As + aOff[i]);
            i32x4 hi = *(const i32x4*)(As + aOff[i] + 1024);
            av[i] = __builtin_shufflevector(lo, hi, 0, 1, 2, 3, 4, 5, 6, 7);
        }
#pragma unroll
        for (int j = 0; j < 4; ++j) {
            i32x4 lo = *(const i32x4*)(Bs + bOff[j]);
            i32x4 hi = *(const i32x4*)(Bs + bOff[j] + 2048);
            i32x8 bv = __builtin_shufflevector(lo, hi, 0, 1, 2, 3, 4, 5, 6, 7);
            acc[0][j] = __builtin_amdgcn_mfma_scale_f32_16x16x128_f8f6f4(
                av[0], bv, acc[0][j], 0, 0, 0, 0x7f7f7f7f, 0, 0x7f7f7f7f);
            acc[1][j] = __builtin_amdgcn_mfma_scale_f32_16x16x128_f8f6f4(
                av[1], bv, acc[1][j], 0, 0, 0, 0x7f7f7f7f, 0, 0x7f7f7f7f);
        }
        __syncthreads();
    }

    // C/D layout: col = lane&15, row = (lane>>4)*4 + reg
    float* Yp = Y + (size_t)part * YPART;
    for (int i = 0; i < 2; ++i) {
        int row = rt * 64 + wm * 32 + i * 16 + quad * 4;
        for (int j = 0; j < 4; ++j) {
            int col = ct * 128 + wn * 64 + j * 16 + l15;
            if (col < 520) {
                for (int r = 0; r < 4; ++r)
                    Yp[(size_t)(row + r) * LDYE + col] = acc[i][j][r];
            }
        }
    }
}

// ---------------------------------------------------------------------------
// K3: out[n, h*64+o] = relu( sum_p Ynum / sum_p Yden )
// ---------------------------------------------------------------------------
__global__ __launch_bounds__(256) void k_epi(const float* __restrict__ Y,
                                             float* __restrict__ out) {
    int idx = blockIdx.x * 256 + threadIdx.x;
    int n = idx >> 7;
    int c = (idx & 127) * 4;
    int h = c >> 6;
    float4 u = {0.f, 0.f, 0.f, 0.f};
    float den = 0.f;
    const float* yp = Y + (size_t)n * LDYE;
#pragma unroll
    for (int p = 0; p < SPLITK; ++p) {
        float4 v = *(const float4*)(yp + c);
        u.x += v.x; u.y += v.y; u.z += v.z; u.w += v.w;
        den += yp[512 + h];
        yp += (size_t)YPART;
    }
    float inv = 1.0f / den;
    float4 o;
    o.x = fmaxf(u.x * inv, 0.f);
    o.y = fmaxf(u.y * inv, 0.f);
    o.z = fmaxf(u.z * inv, 0.f);
    o.w = fmaxf(u.w * inv, 0.f);
    *(float4*)(out + (size_t)n * 512 + c) = o;
}

extern "C" void kernel_launch(void* const* d_in, const int* in_sizes, int n_in,
                              void* d_out, int out_size, void* d_ws, size_t ws_size,
                              hipStream_t stream) {
    const float* X  = (const float*)d_in[0];   // (8192, 512)
    const float* A  = (const float*)d_in[1];   // (8192, 8192)
    const float* Kw = (const float*)d_in[2];   // (8, 512, 64)
    const float* Aw = (const float*)d_in[3];   // (8, 128)
    float* out = (float*)d_out;                // (8192, 512)
    char* ws = (char*)d_ws;
    // ws: Ab 64 MiB | Vt 5 MiB | Yb 2*16.25 MiB (~102 MiB).
    // Xb (8 MiB) + Ktb (0.5 MiB) alias the head of Yb (consumed by k_wx
    // before k_gemm writes Yb).
    unsigned char* Ab = (unsigned char*)ws;
    unsigned char* Vt = (unsigned char*)(ws + (size_t)67108864);
    float* Yb = (float*)(ws + (size_t)67108864 + (size_t)5242880);
    unsigned short* Xb = (unsigned short*)Yb;
    unsigned short* Ktb = Xb + (size_t)NN * FF;

    k_convA8<<<dim3(4096), dim3(256), 0, stream>>>(A, Ab);
    k_prep<<<dim3(2056), dim3(256), 0, stream>>>(X, Kw, Xb, Ktb);
    k_wx<<<dim3(64, 8), dim3(256), 0, stream>>>(Xb, Ktb, Aw, Vt);
    k_gemm<<<dim3(1280), dim3(256), 0, stream>>>(Ab, Vt, Yb);
    k_epi<<<dim3(4096), dim3(256), 0, stream>>>(Yb, out);
}

// Round 7
// 462.456 us; speedup vs baseline: 1.1013x; 1.0342x over previous
//
#include <hip/hip_runtime.h>
#include <cstdint>

// Problem constants
#define NN 8192
#define FF 512
#define FO 64
#define NH 8
#define LDYE 520     // Y row stride: 512 numerator cols + 8 denom cols
#define YPART (8192 * 520)
#define SPLITK 2

// Tiled fp8 layouts (k-major 16-byte granules, staging order).
//  Ab: granule G = (rt*512 + k16)*64 + row   (rt: 0..127, 64-row stripes)
//  Vt: granule H = k16*640 + vrow   (vrow: h*64+o; 512+h = e-row; >=520 junk)
// R17: A stays fp8 (fp4 A produced a deterministic k-permutation error in
// R15/R16 — identical absmax 8.25e-2 across an alignment change proves the
// fp4 operand sub-byte layout assumption is wrong; shelved).

typedef __attribute__((ext_vector_type(8))) __bf16 bf16x8;
typedef __attribute__((ext_vector_type(4))) float f32x4;
typedef __attribute__((ext_vector_type(4))) int i32x4;
typedef __attribute__((ext_vector_type(8))) int i32x8;

__device__ __forceinline__ unsigned short f2bf(float f) {
    unsigned int u = __float_as_uint(f);
    u += 0x7fffu + ((u >> 16) & 1u);
    return (unsigned short)(u >> 16);
}

__device__ __forceinline__ void gload16(const void* g, void* l) {
    __builtin_amdgcn_global_load_lds(
        (const __attribute__((address_space(1))) unsigned int*)g,
        (__attribute__((address_space(3))) unsigned int*)l,
        16, 0, 0);
}

// ---------------------------------------------------------------------------
// K0b: X fp32->bf16; kernels (h,f,o)->Kt (h,o,f) bf16.  (Must precede k_fused:
// the wx path reads Xb/Ktb across the launch boundary.)
// ---------------------------------------------------------------------------
__global__ __launch_bounds__(256) void k_prep(const float* __restrict__ X,
                                              const float* __restrict__ Kw,
                                              unsigned short* __restrict__ Xb,
                                              unsigned short* __restrict__ Ktb) {
    const int b = blockIdx.x;
    const int t = threadIdx.x;
    if (b < 2048) {
        size_t base = ((size_t)b * 256 + t) * 8;
        float4 a = *(const float4*)(X + base);
        float4 c = *(const float4*)(X + base + 4);
        ushort4 o0, o1;
        o0.x = f2bf(a.x); o0.y = f2bf(a.y); o0.z = f2bf(a.z); o0.w = f2bf(a.w);
        o1.x = f2bf(c.x); o1.y = f2bf(c.y); o1.z = f2bf(c.z); o1.w = f2bf(c.w);
        *(ushort4*)(Xb + base) = o0;
        *(ushort4*)(Xb + base + 4) = o1;
    } else {
        int h = b - 2048;
        for (int e = t; e < FF * FO; e += 256) {
            int o = e >> 9, f = e & 511;
            Ktb[(size_t)h * FF * FO + e] = f2bf(Kw[(size_t)h * FF * FO + (size_t)f * FO + o]);
        }
    }
}

// ---------------------------------------------------------------------------
// K_FUSED (R17): wx (ids 0..511) + convA8 (ids 512..4607) in ONE launch.
// conv is HBM-BW-bound (84% peak, 0 MFMA); wx is MFMA/VALU-bound with ~70 MB
// of mostly-cached traffic. They are data-independent, so co-scheduling them
// overlaps wx's compute under conv's memory stalls (serial: ~53+28 us;
// merged floor: max(~59 us BW, compute) ≈ ~60 us). wx blocks are FIRST so
// they land in the first dispatch wave alongside conv blocks.
// Both paths verbatim from their proven versions (R7 wx, R13 conv).
// ---------------------------------------------------------------------------
union WxSmem {
    struct { unsigned short Xs[4096]; unsigned short Ks[2048]; } s;
    unsigned char Vs[64][144];
};
union FusedSmem {
    WxSmem wx;                      // 12 KB
    unsigned char Ls[64][272];      // 17 KB (conv transpose tile)
};

__global__ __launch_bounds__(256) void k_fused(const float* __restrict__ A,
                                               unsigned char* __restrict__ Ab,
                                               const unsigned short* __restrict__ Xb,
                                               const unsigned short* __restrict__ Ktb,
                                               const float* __restrict__ Aw,
                                               unsigned char* __restrict__ Vt) {
    __shared__ FusedSmem fsm;
    const int id = blockIdx.x;
    const int t = threadIdx.x;

    if (id >= 512) {
        // ---- conv path: A fp32 {0,1} -> fp8 (0x00/0x38), tiled Ab ----
        const int cid = id - 512;
        const int rt = cid >> 5;            // 0..127
        const int cb = cid & 31;            // 0..31
        const float* src = A + ((size_t)rt << 19) + ((size_t)cb << 8);
#pragma unroll
        for (int p = 0; p < 16; ++p) {
            int row = p * 4 + (t >> 6);
            int col = (t & 63) * 4;
            uint4 v = *(const uint4*)(src + ((size_t)row << 13) + col);
            unsigned o = ((v.x >> 22) & 0x38u) | (((v.y >> 22) & 0x38u) << 8) |
                         (((v.z >> 22) & 0x38u) << 16) | (((v.w >> 22) & 0x38u) << 24);
            *(unsigned*)&fsm.Ls[row][col] = o;
        }
        __syncthreads();
        unsigned char* dst = Ab + (((size_t)rt * 512 + (size_t)cb * 16) << 10);
#pragma unroll
        for (int j = 0; j < 4; ++j) {
            int g = t + 256 * j;            // 0..1023 = k16l(16) x row(64)
            int row = g & 63, k16l = g >> 6;
            *(uint4*)(dst + ((size_t)g << 4)) = *(const uint4*)&fsm.Ls[row][k16l * 16];
        }
        return;
    }

    // ---- wx path: WX = Xb @ Kt^T (bf16 MFMA), e=exp(s2), fp8 V -> Vt ----
    WxSmem& sm = fsm.wx;
    const int n0 = (id & 63) * 128;
    const int h = id >> 6;                  // 0..7
    const int lane = t & 63, w = t >> 6;
    const int quad = lane >> 4, l15 = lane & 15;

    const unsigned short* xS0 = Xb + (size_t)(n0 + (t & 127)) * FF + (t >> 7) * 8;
    const unsigned short* xS1 = Xb + (size_t)(n0 + ((t + 256) & 127)) * FF + ((t + 256) >> 7) * 8;
    unsigned short* xD0 = sm.s.Xs + t * 8;
    unsigned short* xD1 = sm.s.Xs + (t + 256) * 8;
    const unsigned short* kS = Ktb + (size_t)h * FF * FO + (size_t)(t & 63) * FF + (t >> 6) * 8;
    unsigned short* kD = sm.s.Ks + t * 8;

    const bf16x8* aF[2];
    const bf16x8* bF[4];
    for (int i = 0; i < 2; ++i)
        aF[i] = (const bf16x8*)(sm.s.Xs + (size_t)(quad * 128 + w * 32 + i * 16 + l15) * 8);
    for (int j = 0; j < 4; ++j)
        bF[j] = (const bf16x8*)(sm.s.Ks + (size_t)(quad * 64 + j * 16 + l15) * 8);

    f32x4 acc[2][4] = {};
    for (int f0 = 0; f0 < FF; f0 += 32) {
        gload16(xS0 + f0, xD0);
        gload16(xS1 + f0, xD1);
        gload16(kS + f0, kD);
        __syncthreads();
        bf16x8 av[2], bv[4];
        for (int i = 0; i < 2; ++i) av[i] = aF[i][0];
        for (int j = 0; j < 4; ++j) bv[j] = bF[j][0];
        for (int i = 0; i < 2; ++i)
            for (int j = 0; j < 4; ++j)
                acc[i][j] = __builtin_amdgcn_mfma_f32_16x16x32_bf16(av[i], bv[j], acc[i][j], 0, 0, 0);
        __syncthreads();
    }

    float a2v[4];
    for (int j = 0; j < 4; ++j) a2v[j] = Aw[h * 128 + 64 + j * 16 + l15];
    float ex[2][4];
    for (int i = 0; i < 2; ++i)
        for (int r = 0; r < 4; ++r) {
            float p = acc[i][0][r] * a2v[0] + acc[i][1][r] * a2v[1]
                    + acc[i][2][r] * a2v[2] + acc[i][3][r] * a2v[3];
            p += __shfl_xor(p, 1);
            p += __shfl_xor(p, 2);
            p += __shfl_xor(p, 4);
            p += __shfl_xor(p, 8);
            ex[i][r] = __expf(p);
        }

    for (int i = 0; i < 2; ++i)
        for (int j = 0; j < 4; ++j) {
            int rowb = w * 32 + i * 16 + quad * 4;
            int col = j * 16 + l15;
            unsigned u = __builtin_amdgcn_cvt_pk_fp8_f32(
                ex[i][0] * acc[i][j][0], ex[i][1] * acc[i][j][1], 0, false);
            u = __builtin_amdgcn_cvt_pk_fp8_f32(
                ex[i][2] * acc[i][j][2], ex[i][3] * acc[i][j][3], (int)u, true);
            *(unsigned*)&sm.Vs[col][rowb] = u;
        }
    __syncthreads();
    for (int j2 = 0; j2 < 2; ++j2) {
        int vid = t + j2 * 256;            // 0..511 = 64 o x 8 k16o (uint4)
        int o = vid >> 3, k16o = vid & 7;
        size_t H = (size_t)((n0 >> 4) + k16o) * 640 + h * 64 + o;
        *(uint4*)(Vt + (H << 4)) = *(const uint4*)&sm.Vs[o][k16o * 16];
    }
    if (l15 == 0) {
        for (int i = 0; i < 2; ++i)
            for (int r = 0; r < 4; ++r) {
                int row = w * 32 + i * 16 + quad * 4 + r;
                unsigned u = __builtin_amdgcn_cvt_pk_fp8_f32(ex[i][r], ex[i][r], 0, false);
                size_t H = (size_t)((n0 >> 4) + (row >> 4)) * 640 + 512 + h;
                Vt[(H << 4) + (row & 15)] = (unsigned char)(u & 0xff);
            }
    }
}

// ---------------------------------------------------------------------------
// K2 (R14, proven): MX-scaled fp8 K=128 MFMA (scales = e8m0 1.0, exact).
// BM=64, BN=128 (5 ct over N=640), SPLITK=2 -> grid 1280 = exactly 5/CU.
// LDS 24 KB; acc 2x4 (32 AGPR); A = 2 gload16/iter, B = 4.
// ---------------------------------------------------------------------------
__global__ __launch_bounds__(256, 5) void k_gemm(const unsigned char* __restrict__ Ab,
                                                 const unsigned char* __restrict__ Vt,
                                                 float* __restrict__ Y) {
    __shared__ unsigned char As[8192];    // kq(8) x row(64) x 16 B
    __shared__ unsigned char Bs[16384];   // kq(8) x n(128) x 16 B
    const int t = threadIdx.x;
    const int id = blockIdx.x;
    const int xcd = id & 7;
    const int u = id >> 3;                 // 0..159
    const int ct = u % 5;                  // 0..4
    const int rp = (u / 5) * 8 + xcd;      // 0..255
    const int rt = rp & 127;               // 0..127
    const int part = rp >> 7;              // 0..1
    const int ks0 = part * 32;             // 64 iters of BK=128 total
    const int ks1 = ks0 + 32;

    // A staging: 2 gload16 cover the 8 KB tile (granules t and t+256).
    const unsigned char* aS = Ab + ((size_t)rt << 19) + (size_t)t * 16;
    unsigned char* aD0 = As + t * 16;
    unsigned char* aD1 = As + t * 16 + 4096;
    // B staging: granule g = t + 256j (0..1023); kq = g>>7, n = g&127.
    const unsigned char* bS[4];
    unsigned char* bD[4];
#pragma unroll
    for (int j = 0; j < 4; ++j) {
        int g = t + 256 * j;
        bS[j] = Vt + (size_t)((g >> 7) * 640 + ct * 128 + (g & 127)) * 16;
        bD[j] = Bs + g * 16;
    }

    const int lane = t & 63;
    const int w = t >> 6;
    const int wm = w >> 1, wn = w & 1;
    const int quad = lane >> 4, l15 = lane & 15;

    // fragment byte offsets: lane's 32 k-bytes = granules kq=quad*2, quad*2+1
    int aOff[2], bOff[4];
#pragma unroll
    for (int i = 0; i < 2; ++i)
        aOff[i] = quad * 2048 + (wm * 32 + i * 16 + l15) * 16;
#pragma unroll
    for (int j = 0; j < 4; ++j)
        bOff[j] = quad * 4096 + (wn * 64 + j * 16 + l15) * 16;

    f32x4 acc[2][4] = {};

    for (int ks = ks0; ks < ks1; ++ks) {
        const size_t koA = (size_t)ks << 13;       // *8192
        const size_t koB = (size_t)ks * 81920;     // *8*640*16
        gload16(aS + koA, aD0);
        gload16(aS + koA + 4096, aD1);
#pragma unroll
        for (int j = 0; j < 4; ++j) gload16(bS[j] + koB, bD[j]);
        __syncthreads();
        i32x8 av[2];
#pragma unroll
        for (int i = 0; i < 2; ++i) {
            i32x4 lo = *(const i32x4*)(As + aOff[i]);
            i32x4 hi = *(const i32x4*)(As + aOff[i] + 1024);
            av[i] = __builtin_shufflevector(lo, hi, 0, 1, 2, 3, 4, 5, 6, 7);
        }
#pragma unroll
        for (int j = 0; j < 4; ++j) {
            i32x4 lo = *(const i32x4*)(Bs + bOff[j]);
            i32x4 hi = *(const i32x4*)(Bs + bOff[j] + 2048);
            i32x8 bv = __builtin_shufflevector(lo, hi, 0, 1, 2, 3, 4, 5, 6, 7);
            acc[0][j] = __builtin_amdgcn_mfma_scale_f32_16x16x128_f8f6f4(
                av[0], bv, acc[0][j], 0, 0, 0, 0x7f7f7f7f, 0, 0x7f7f7f7f);
            acc[1][j] = __builtin_amdgcn_mfma_scale_f32_16x16x128_f8f6f4(
                av[1], bv, acc[1][j], 0, 0, 0, 0x7f7f7f7f, 0, 0x7f7f7f7f);
        }
        __syncthreads();
    }

    // C/D layout: col = lane&15, row = (lane>>4)*4 + reg
    float* Yp = Y + (size_t)part * YPART;
    for (int i = 0; i < 2; ++i) {
        int row = rt * 64 + wm * 32 + i * 16 + quad * 4;
        for (int j = 0; j < 4; ++j) {
            int col = ct * 128 + wn * 64 + j * 16 + l15;
            if (col < 520) {
                for (int r = 0; r < 4; ++r)
                    Yp[(size_t)(row + r) * LDYE + col] = acc[i][j][r];
            }
        }
    }
}

// ---------------------------------------------------------------------------
// K3: out[n, h*64+o] = relu( sum_p Ynum / sum_p Yden )
// ---------------------------------------------------------------------------
__global__ __launch_bounds__(256) void k_epi(const float* __restrict__ Y,
                                             float* __restrict__ out) {
    int idx = blockIdx.x * 256 + threadIdx.x;
    int n = idx >> 7;
    int c = (idx & 127) * 4;
    int h = c >> 6;
    float4 u = {0.f, 0.f, 0.f, 0.f};
    float den = 0.f;
    const float* yp = Y + (size_t)n * LDYE;
#pragma unroll
    for (int p = 0; p < SPLITK; ++p) {
        float4 v = *(const float4*)(yp + c);
        u.x += v.x; u.y += v.y; u.z += v.z; u.w += v.w;
        den += yp[512 + h];
        yp += (size_t)YPART;
    }
    float inv = 1.0f / den;
    float4 o;
    o.x = fmaxf(u.x * inv, 0.f);
    o.y = fmaxf(u.y * inv, 0.f);
    o.z = fmaxf(u.z * inv, 0.f);
    o.w = fmaxf(u.w * inv, 0.f);
    *(float4*)(out + (size_t)n * 512 + c) = o;
}

extern "C" void kernel_launch(void* const* d_in, const int* in_sizes, int n_in,
                              void* d_out, int out_size, void* d_ws, size_t ws_size,
                              hipStream_t stream) {
    const float* X  = (const float*)d_in[0];   // (8192, 512)
    const float* A  = (const float*)d_in[1];   // (8192, 8192)
    const float* Kw = (const float*)d_in[2];   // (8, 512, 64)
    const float* Aw = (const float*)d_in[3];   // (8, 128)
    float* out = (float*)d_out;                // (8192, 512)
    char* ws = (char*)d_ws;
    // ws: Ab 64 MiB | Vt 5 MiB | Yb 2*16.25 MiB (~102 MiB).
    // Xb (8 MiB) + Ktb (0.5 MiB) alias the head of Yb (consumed by k_fused
    // before k_gemm writes Yb).
    unsigned char* Ab = (unsigned char*)ws;
    unsigned char* Vt = (unsigned char*)(ws + (size_t)67108864);
    float* Yb = (float*)(ws + (size_t)67108864 + (size_t)5242880);
    unsigned short* Xb = (unsigned short*)Yb;
    unsigned short* Ktb = Xb + (size_t)NN * FF;

    k_prep<<<dim3(2056), dim3(256), 0, stream>>>(X, Kw, Xb, Ktb);
    k_fused<<<dim3(4608), dim3(256), 0, stream>>>(A, Ab, Xb, Ktb, Aw, Vt);
    k_gemm<<<dim3(1280), dim3(256), 0, stream>>>(Ab, Vt, Yb);
    k_epi<<<dim3(4096), dim3(256), 0, stream>>>(Yb, out);
}